// Round 3
// baseline (132.423 us; speedup 1.0000x reference)
//
#include <hip/hip_runtime.h>

#define NN 10000
#define EE 160000
#define DD 512
#define CAP 128   // bucket capacity; deg ~ Poisson(16), P(>=128) ~ 0 (writes clamped)

typedef float floatx4 __attribute__((ext_vector_type(4)));
typedef short short8 __attribute__((ext_vector_type(8)));

#define AS3(p) ((__attribute__((address_space(3))) void*)(p))
#define AS1(p) ((const __attribute__((address_space(1))) void*)(p))

static __device__ __forceinline__ unsigned short f2bf(float f) {
    unsigned int u = __float_as_uint(f);
    unsigned int r = (u + 0x7fffu + ((u >> 16) & 1u)) >> 16;
    return (unsigned short)r;
}
// HW packed convert: lo16 = bf16(a), hi16 = bf16(b). RNE, 1 instr (gfx950; no builtin).
static __device__ __forceinline__ unsigned int cvtpk(float a, float b) {
    unsigned int r;
    asm("v_cvt_pk_bf16_f32 %0, %1, %2" : "=v"(r) : "v"(a), "v"(b));
    return r;
}
static __device__ __forceinline__ float bflo(unsigned int u) {
    return __uint_as_float(u << 16);
}
static __device__ __forceinline__ float bfhi(unsigned int u) {
    return __uint_as_float(u & 0xffff0000u);
}

// ---------------- k0: W->W^T bf16 (LDS-tiled) + zero deg/cursor ----------------

#define WT_BLOCKS 256
#define ZERO_BLOCKS 20
#define EDGE_BLOCKS 625
#define GM_BLOCKS (157 * 4)   // 64-row tiles x 4 col-tiles of 128

__global__ __launch_bounds__(256) void k_prep_w(const float* __restrict__ W,
                                                unsigned short* __restrict__ wtb,
                                                uint4* __restrict__ zbase) {
    const int b = blockIdx.x;
    const int tid = threadIdx.x;
    if (b < WT_BLOCKS) {
        __shared__ float T[32][33];
        int bi = b & 15;          // k-tile
        int bj = b >> 4;          // n-tile
        int r0 = tid >> 5;        // 0..7
        int cc = tid & 31;
        #pragma unroll
        for (int k = 0; k < 4; k++) {
            int r = r0 + k * 8;
            T[r][cc] = W[(size_t)(bi * 32 + r) * DD + bj * 32 + cc];
        }
        __syncthreads();
        #pragma unroll
        for (int k = 0; k < 4; k++) {
            int r = r0 + k * 8;
            wtb[(size_t)(bj * 32 + r) * DD + bi * 32 + cc] = f2bf(T[cc][r]);   // wtb[n][k]=W[k][n]
        }
    } else {
        // zero deg + cursor: 20 blocks x 256 thr x 16 B = 81920 B
        int idx = (b - WT_BLOCKS) * 256 + tid;
        zbase[idx] = make_uint4(0u, 0u, 0u, 0u);
    }
}

// ---------------- fused: edge bucket/deg build (625 blocks) + MFMA GEMM (628 blocks) ----------------
// GEMM stages A directly from x (f32 -> v_cvt_pk_bf16_f32 -> ds_write_b128): no xb pass.
// GEMM has no dependency on deg -> latency-bound edge atomics overlap with MFMA blocks.

__global__ __launch_bounds__(256) void k_gemm_edge(const float* __restrict__ x,
                                                   const unsigned short* __restrict__ wtb,
                                                   unsigned short* __restrict__ hb,
                                                   const int* __restrict__ row,
                                                   const int* __restrict__ col,
                                                   const float* __restrict__ ew,
                                                   float* __restrict__ deg,
                                                   int* __restrict__ cursor,
                                                   uint2* __restrict__ erw) {
    __shared__ unsigned short As[64 * 32];    // 4 KB
    __shared__ unsigned short Bs[128 * 32];   // 8 KB

    const int tid = threadIdx.x;

    if (blockIdx.x < EDGE_BLOCKS) {
        // -------- edge pass: deg accum + bucket build --------
        int e = blockIdx.x * 256 + tid;        // exactly covers EE
        int r = row[e];
        int t = col[e];
        float w = ew[e];
        atomicAdd(&deg[t], w);
        int p = atomicAdd(&cursor[t], 1);
        if (p < CAP) erw[t * CAP + p] = make_uint2((unsigned int)r, __float_as_uint(w));
        return;
    }

    // -------- GEMM: hb = bf16(x @ W), 64x128 tile --------
    const int bid = blockIdx.x - EDGE_BLOCKS;
    const int wave = tid >> 6;
    const int lane = tid & 63;

    const int bm = (bid >> 2) * 64;
    const int bn = (bid & 3) * 128;

    const int wm = (wave >> 1) * 32;   // 0 / 32
    const int wn = (wave & 1) * 64;    // 0 / 64

    const int fm = lane & 15;
    const int kb = (lane >> 4) * 8;

    floatx4 acc[2][4];
    #pragma unroll
    for (int i = 0; i < 2; i++)
        #pragma unroll
        for (int j = 0; j < 4; j++)
            acc[i][j] = (floatx4){0.f, 0.f, 0.f, 0.f};

    const int srow = lane >> 2;          // 0..15 within a 16-row chunk
    const int scol = (lane & 3) * 8;     // 0,8,16,24

    // per-thread A source row (fixed across K-loop)
    int gr = bm + wave * 16 + srow; if (gr > NN - 1) gr = NN - 1;   // clamp (stores guarded)
    const float* xrow = x + (size_t)gr * DD + scol;

    for (int k0 = 0; k0 < DD; k0 += 32) {
        // A: 64 rows from x f32, HW packed convert, ds_write_b128
        {
            float4 v0 = *(const float4*)(xrow + k0);
            float4 v1 = *(const float4*)(xrow + k0 + 4);
            unsigned int u0 = cvtpk(v0.x, v0.y);
            unsigned int u1 = cvtpk(v0.z, v0.w);
            unsigned int u2 = cvtpk(v1.x, v1.y);
            unsigned int u3 = cvtpk(v1.z, v1.w);
            *(uint4*)&As[(size_t)(wave * 16 + srow) * 32 + scol] = make_uint4(u0, u1, u2, u3);
        }
        // B: 128 rows, two chunks per wave, async global->LDS
        #pragma unroll
        for (int cc = 0; cc < 2; cc++) {
            int c = wave + cc * 4;
            int nr = bn + c * 16 + srow;
            __builtin_amdgcn_global_load_lds(AS1(wtb + (size_t)nr * DD + k0 + scol),
                                             AS3(&Bs[c * 512]), 16, 0, 0);
        }
        __syncthreads();

        short8 af[2], bfr[4];
        #pragma unroll
        for (int mi = 0; mi < 2; mi++)
            af[mi] = *(const short8*)&As[(wm + mi * 16 + fm) * 32 + kb];
        #pragma unroll
        for (int ni = 0; ni < 4; ni++)
            bfr[ni] = *(const short8*)&Bs[(wn + ni * 16 + fm) * 32 + kb];

        #pragma unroll
        for (int mi = 0; mi < 2; mi++)
            #pragma unroll
            for (int ni = 0; ni < 4; ni++)
                acc[mi][ni] = __builtin_amdgcn_mfma_f32_16x16x32_bf16(af[mi], bfr[ni], acc[mi][ni], 0, 0, 0);

        __syncthreads();
    }

    #pragma unroll
    for (int mi = 0; mi < 2; mi++) {
        #pragma unroll
        for (int ni = 0; ni < 4; ni++) {
            int colg = bn + wn + ni * 16 + (lane & 15);
            int rbase = bm + wm + mi * 16 + (lane >> 4) * 4;
            #pragma unroll
            for (int j = 0; j < 4; j += 2) {
                unsigned int u = cvtpk(acc[mi][ni][j], acc[mi][ni][j + 1]);
                int rg = rbase + j;
                if (rg < NN)     hb[(size_t)rg * DD + colg]       = (unsigned short)(u & 0xffffu);
                if (rg + 1 < NN) hb[(size_t)(rg + 1) * DD + colg] = (unsigned short)(u >> 16);
            }
        }
    }
}

// ---------------- aggregate: column-half split, XCD-parity placement ----------------
// Block bid (128 thr = 2 waves): half = bid&1, wave h handles node (bid>>1)*2 + h,
// columns [half*256, half*256+256), 4 bf16 cols/lane (uint2 gathers, 512 B/row/wave).
// dinv[row] folded at bucket-stage time (s_w = w * rsqrt(deg[r]+1)); hb holds raw h.

#define EDGE_FMA2(P, W) \
    acc[0] += bflo(P.x) * W; acc[1] += bfhi(P.x) * W; \
    acc[2] += bflo(P.y) * W; acc[3] += bfhi(P.y) * W;

__global__ __launch_bounds__(128, 8) void k_aggregate(const int* __restrict__ cursor,
                                                      const uint2* __restrict__ erw,
                                                      const unsigned short* __restrict__ hb,
                                                      const float* __restrict__ deg,
                                                      const float* __restrict__ bias,
                                                      float* __restrict__ out) {
    const int h = threadIdx.x >> 6;
    const int t = threadIdx.x & 63;
    const int bid = blockIdx.x;                // 0..9999
    const int half = bid & 1;
    const int i = (bid >> 1) * 2 + h;          // node
    const int c = half * 256 + t * 4;          // bf16 col index, 4 cols/lane

    __shared__ int   s_r[2][CAP];              // precomputed row*DD element base
    __shared__ float s_w[2][CAP];

    int cnt = cursor[i];
    if (cnt > CAP) cnt = CAP;
    const uint2* bkt = erw + (size_t)i * CAP;
    if (t < cnt) {
        uint2 p = bkt[t];
        int r = (int)p.x;
        s_r[h][t] = r << 9;                    // r * DD
        s_w[h][t] = __uint_as_float(p.y) * rsqrtf(deg[r] + 1.0f);
    }
    if (t + 64 < cnt) {
        uint2 p = bkt[t + 64];
        int r = (int)p.x;
        s_r[h][t + 64] = r << 9;
        s_w[h][t + 64] = __uint_as_float(p.y) * rsqrtf(deg[r] + 1.0f);
    }

    // hoist self-row + bias
    float dv = rsqrtf(deg[i] + 1.0f);
    uint2 hv = *(const uint2*)&hb[(size_t)i * DD + c];
    float4 bv = *(const float4*)&bias[c];

    __syncthreads();

    float acc[4] = {0.f, 0.f, 0.f, 0.f};

    int j = 0;
    for (; j + 8 <= cnt; j += 8) {
        uint2 p0 = *(const uint2*)&hb[s_r[h][j    ] + c];
        uint2 p1 = *(const uint2*)&hb[s_r[h][j + 1] + c];
        uint2 p2 = *(const uint2*)&hb[s_r[h][j + 2] + c];
        uint2 p3 = *(const uint2*)&hb[s_r[h][j + 3] + c];
        uint2 p4 = *(const uint2*)&hb[s_r[h][j + 4] + c];
        uint2 p5 = *(const uint2*)&hb[s_r[h][j + 5] + c];
        uint2 p6 = *(const uint2*)&hb[s_r[h][j + 6] + c];
        uint2 p7 = *(const uint2*)&hb[s_r[h][j + 7] + c];
        float w0 = s_w[h][j],     w1 = s_w[h][j + 1], w2 = s_w[h][j + 2], w3 = s_w[h][j + 3];
        float w4 = s_w[h][j + 4], w5 = s_w[h][j + 5], w6 = s_w[h][j + 6], w7 = s_w[h][j + 7];
        EDGE_FMA2(p0, w0) EDGE_FMA2(p1, w1) EDGE_FMA2(p2, w2) EDGE_FMA2(p3, w3)
        EDGE_FMA2(p4, w4) EDGE_FMA2(p5, w5) EDGE_FMA2(p6, w6) EDGE_FMA2(p7, w7)
    }
    for (; j + 4 <= cnt; j += 4) {
        uint2 p0 = *(const uint2*)&hb[s_r[h][j    ] + c];
        uint2 p1 = *(const uint2*)&hb[s_r[h][j + 1] + c];
        uint2 p2 = *(const uint2*)&hb[s_r[h][j + 2] + c];
        uint2 p3 = *(const uint2*)&hb[s_r[h][j + 3] + c];
        float w0 = s_w[h][j], w1 = s_w[h][j + 1], w2 = s_w[h][j + 2], w3 = s_w[h][j + 3];
        EDGE_FMA2(p0, w0) EDGE_FMA2(p1, w1) EDGE_FMA2(p2, w2) EDGE_FMA2(p3, w3)
    }
    for (; j < cnt; j++) {
        uint2 p0 = *(const uint2*)&hb[s_r[h][j] + c];
        float w0 = s_w[h][j];
        EDGE_FMA2(p0, w0)
    }

    float2 o0, o1;
    o0.x = (acc[0] + bflo(hv.x) * dv) * dv + bv.x;
    o0.y = (acc[1] + bfhi(hv.x) * dv) * dv + bv.y;
    o1.x = (acc[2] + bflo(hv.y) * dv) * dv + bv.z;
    o1.y = (acc[3] + bfhi(hv.y) * dv) * dv + bv.w;
    *(float2*)&out[(size_t)i * DD + c] = o0;
    *(float2*)&out[(size_t)i * DD + c + 2] = o1;
}

extern "C" void kernel_launch(void* const* d_in, const int* in_sizes, int n_in,
                              void* d_out, int out_size, void* d_ws, size_t ws_size,
                              hipStream_t stream) {
    const float* x  = (const float*)d_in[0];
    const int*   ei = (const int*)d_in[1];
    const float* ea = (const float*)d_in[2];
    const float* W  = (const float*)d_in[3];
    const float* b  = (const float*)d_in[4];
    float* out = (float*)d_out;

    char* ws = (char*)d_ws;
    unsigned short* hb   = (unsigned short*)ws;                 // 10,240,000 B
    unsigned short* wtb  = (unsigned short*)(ws + 20480000);    // 524,288 B
    float* deg    = (float*)(ws + 21004288);                    // 40,960 B
    int*   cursor = (int*)  (ws + 21045248);                    // 40,960 B
    uint2* erw    = (uint2*)(ws + 21086208);                    // 10,240,000 B

    const int* row = ei;
    const int* col = ei + EE;

    k_prep_w<<<WT_BLOCKS + ZERO_BLOCKS, 256, 0, stream>>>(W, wtb, (uint4*)deg);

    k_gemm_edge<<<EDGE_BLOCKS + GM_BLOCKS, 256, 0, stream>>>(x, wtb, hb, row, col, ea,
                                                             deg, cursor, erw);

    k_aggregate<<<NN, 128, 0, stream>>>(cursor, erw, hb, deg, b, out);
}

// Round 4
// 131.995 us; speedup vs baseline: 1.0032x; 1.0032x over previous
//
#include <hip/hip_runtime.h>

#define NN 10000
#define EE 160000
#define DD 512
#define CAP 128   // bucket capacity; deg ~ Poisson(16), P(>=128) ~ 0 (writes clamped)

typedef float floatx4 __attribute__((ext_vector_type(4)));
typedef short short8 __attribute__((ext_vector_type(8)));

#define AS3(p) ((__attribute__((address_space(3))) void*)(p))
#define AS1(p) ((const __attribute__((address_space(1))) void*)(p))

static __device__ __forceinline__ unsigned short f2bf(float f) {
    unsigned int u = __float_as_uint(f);
    unsigned int r = (u + 0x7fffu + ((u >> 16) & 1u)) >> 16;
    return (unsigned short)r;
}
// HW packed convert: lo16 = bf16(a), hi16 = bf16(b). RNE, 1 instr (gfx950; no builtin).
static __device__ __forceinline__ unsigned int cvtpk(float a, float b) {
    unsigned int r;
    asm("v_cvt_pk_bf16_f32 %0, %1, %2" : "=v"(r) : "v"(a), "v"(b));
    return r;
}
static __device__ __forceinline__ float bflo(unsigned int u) {
    return __uint_as_float(u << 16);
}
static __device__ __forceinline__ float bfhi(unsigned int u) {
    return __uint_as_float(u & 0xffff0000u);
}

// ---------------- prep: x->bf16 (BW-bound) | W->W^T bf16 (LDS-tiled) ----------------

#define XB_BLOCKS 5000
#define WT_BLOCKS 256
// Edge blocks padded to a multiple of 8 so the GEMM blocks that follow keep
// col-tile q on XCDs {q, q+4} under round-robin dispatch — the same XCDs the
// quarter-split aggregate reads quarter q from (write-side L2 locality).
#define EDGE_BLOCKS 632
#define GM_BLOCKS (157 * 4)   // 64-row tiles x 4 col-tiles of 128

__global__ __launch_bounds__(256) void k_prep_xw(const float* __restrict__ x,
                                                 const float* __restrict__ W,
                                                 unsigned short* __restrict__ xb,
                                                 unsigned short* __restrict__ wtb) {
    const int b = blockIdx.x;
    const int tid = threadIdx.x;
    if (b < XB_BLOCKS) {
        int gid = b * 256 + tid;                     // float4 group of x
        float4 v = *(const float4*)&x[(size_t)gid * 4];
        *(uint2*)&xb[(size_t)gid * 4] = make_uint2(cvtpk(v.x, v.y), cvtpk(v.z, v.w));
    } else {
        __shared__ float T[32][33];
        int idx = b - XB_BLOCKS;
        int bi = idx & 15;        // k-tile
        int bj = idx >> 4;        // n-tile
        int r0 = tid >> 5;        // 0..7
        int cc = tid & 31;
        #pragma unroll
        for (int k = 0; k < 4; k++) {
            int r = r0 + k * 8;
            T[r][cc] = W[(size_t)(bi * 32 + r) * DD + bj * 32 + cc];
        }
        __syncthreads();
        #pragma unroll
        for (int k = 0; k < 4; k++) {
            int r = r0 + k * 8;
            wtb[(size_t)(bj * 32 + r) * DD + bi * 32 + cc] = f2bf(T[cc][r]);   // wtb[n][k]=W[k][n]
        }
    }
}

// ---------------- fused: edge bucket/deg build (632 blocks) + MFMA GEMM (628 blocks) ----------------
// GEMM: double-buffered LDS staging (stage k+1 issued right after the single
// per-step barrier, flies under compute of step k). A from xb bf16, async lds.

__global__ __launch_bounds__(256) void k_gemm_edge(const unsigned short* __restrict__ xb,
                                                   const unsigned short* __restrict__ wtb,
                                                   unsigned short* __restrict__ hb,
                                                   const int* __restrict__ row,
                                                   const int* __restrict__ col,
                                                   const float* __restrict__ ew,
                                                   float* __restrict__ deg,
                                                   int* __restrict__ cursor,
                                                   uint2* __restrict__ erw) {
    __shared__ unsigned short As[2][64 * 32];    // 2 x 4 KB
    __shared__ unsigned short Bs[2][128 * 32];   // 2 x 8 KB

    const int tid = threadIdx.x;

    if (blockIdx.x < EDGE_BLOCKS) {
        // -------- edge pass: deg accum + bucket build --------
        int e = blockIdx.x * 256 + tid;
        if (e < EE) {
            int r = row[e];
            int t = col[e];
            float w = ew[e];
            atomicAdd(&deg[t], w);
            int p = atomicAdd(&cursor[t], 1);
            if (p < CAP) erw[t * CAP + p] = make_uint2((unsigned int)r, __float_as_uint(w));
        }
        return;
    }

    // -------- GEMM: hb = bf16(xb @ wtb^T), 64x128 tile --------
    const int bid = blockIdx.x - EDGE_BLOCKS;
    const int wave = tid >> 6;
    const int lane = tid & 63;

    const int bm = (bid >> 2) * 64;
    const int bn = (bid & 3) * 128;

    const int wm = (wave >> 1) * 32;   // 0 / 32
    const int wn = (wave & 1) * 64;    // 0 / 64

    const int fm = lane & 15;
    const int kb = (lane >> 4) * 8;

    floatx4 acc[2][4];
    #pragma unroll
    for (int i = 0; i < 2; i++)
        #pragma unroll
        for (int j = 0; j < 4; j++)
            acc[i][j] = (floatx4){0.f, 0.f, 0.f, 0.f};

    const int srow = lane >> 2;          // 0..15 within a 16-row chunk
    const int scol = (lane & 3) * 8;     // 0,8,16,24

    int gr = bm + wave * 16 + srow; if (gr > NN - 1) gr = NN - 1;   // clamp (stores guarded)

#define STAGE(buf, k0) do {                                                          \
        __builtin_amdgcn_global_load_lds(AS1(xb + (size_t)gr * DD + (k0) + scol),    \
                                         AS3(&As[buf][wave * 512]), 16, 0, 0);       \
        _Pragma("unroll")                                                            \
        for (int cc = 0; cc < 2; cc++) {                                             \
            int c = wave + cc * 4;                                                   \
            int nr = bn + c * 16 + srow;                                             \
            __builtin_amdgcn_global_load_lds(AS1(wtb + (size_t)nr * DD + (k0) + scol), \
                                             AS3(&Bs[buf][c * 512]), 16, 0, 0);      \
        }                                                                            \
    } while (0)

    STAGE(0, 0);

    for (int k = 0; k < 16; k++) {
        const int buf = k & 1;
        __syncthreads();                        // drains stage(k) vmcnt + prior ds_reads
        if (k < 15) STAGE(buf ^ 1, (k + 1) * 32);   // flies under this step's compute

        short8 af[2], bfr[4];
        #pragma unroll
        for (int mi = 0; mi < 2; mi++)
            af[mi] = *(const short8*)&As[buf][(wm + mi * 16 + fm) * 32 + kb];
        #pragma unroll
        for (int ni = 0; ni < 4; ni++)
            bfr[ni] = *(const short8*)&Bs[buf][(wn + ni * 16 + fm) * 32 + kb];

        #pragma unroll
        for (int mi = 0; mi < 2; mi++)
            #pragma unroll
            for (int ni = 0; ni < 4; ni++)
                acc[mi][ni] = __builtin_amdgcn_mfma_f32_16x16x32_bf16(af[mi], bfr[ni], acc[mi][ni], 0, 0, 0);
    }
#undef STAGE

    #pragma unroll
    for (int mi = 0; mi < 2; mi++) {
        #pragma unroll
        for (int ni = 0; ni < 4; ni++) {
            int colg = bn + wn + ni * 16 + (lane & 15);
            int rbase = bm + wm + mi * 16 + (lane >> 4) * 4;
            #pragma unroll
            for (int j = 0; j < 4; j++) {
                int rg = rbase + j;
                if (rg < NN) hb[(size_t)rg * DD + colg] = f2bf(acc[mi][ni][j]);
            }
        }
    }
}

// ---------------- aggregate: column-QUARTER split, XCD binding ----------------
// Block bid (128 thr = 2 waves): quarter q = bid&3, wave h handles node (bid>>2)*2 + h,
// columns [q*128, q*128+128), 2 bf16 cols/lane. Round-robin dispatch puts quarter q
// on XCDs {q, q+4} -> per-XCD hb working set 2.56 MB < 4 MB L2 -> gathers L2-resident.
// dinv[row] folded at bucket-stage time; hb holds raw h.

#define EDGE_FMA(P, W) a0 += bflo(P) * W; a1 += bfhi(P) * W;

__global__ __launch_bounds__(128, 8) void k_aggregate(const int* __restrict__ cursor,
                                                      const uint2* __restrict__ erw,
                                                      const unsigned short* __restrict__ hb,
                                                      const float* __restrict__ deg,
                                                      const float* __restrict__ bias,
                                                      float* __restrict__ out) {
    const int h = threadIdx.x >> 6;
    const int t = threadIdx.x & 63;
    const int bid = blockIdx.x;                // 0..19999
    const int q = bid & 3;
    const int i = (bid >> 2) * 2 + h;          // node
    const int c = q * 128 + t * 2;             // bf16 col index, 2 cols/lane

    __shared__ int   s_r[2][CAP];              // precomputed row*DD element base
    __shared__ float s_w[2][CAP];

    int cnt = cursor[i];
    if (cnt > CAP) cnt = CAP;
    const uint2* bkt = erw + (size_t)i * CAP;
    if (t < cnt) {
        uint2 p = bkt[t];
        int r = (int)p.x;
        s_r[h][t] = r << 9;                    // r * DD
        s_w[h][t] = __uint_as_float(p.y) * rsqrtf(deg[r] + 1.0f);
    }
    if (t + 64 < cnt) {
        uint2 p = bkt[t + 64];
        int r = (int)p.x;
        s_r[h][t + 64] = r << 9;
        s_w[h][t + 64] = __uint_as_float(p.y) * rsqrtf(deg[r] + 1.0f);
    }

    // hoist self-row + bias
    float dv = rsqrtf(deg[i] + 1.0f);
    unsigned int hv = *(const unsigned int*)&hb[(size_t)i * DD + c];
    float2 bv = *(const float2*)&bias[c];

    __syncthreads();

    float a0 = 0.f, a1 = 0.f;

    int j = 0;
    for (; j + 8 <= cnt; j += 8) {
        unsigned int p0 = *(const unsigned int*)&hb[s_r[h][j    ] + c];
        unsigned int p1 = *(const unsigned int*)&hb[s_r[h][j + 1] + c];
        unsigned int p2 = *(const unsigned int*)&hb[s_r[h][j + 2] + c];
        unsigned int p3 = *(const unsigned int*)&hb[s_r[h][j + 3] + c];
        unsigned int p4 = *(const unsigned int*)&hb[s_r[h][j + 4] + c];
        unsigned int p5 = *(const unsigned int*)&hb[s_r[h][j + 5] + c];
        unsigned int p6 = *(const unsigned int*)&hb[s_r[h][j + 6] + c];
        unsigned int p7 = *(const unsigned int*)&hb[s_r[h][j + 7] + c];
        float w0 = s_w[h][j],     w1 = s_w[h][j + 1], w2 = s_w[h][j + 2], w3 = s_w[h][j + 3];
        float w4 = s_w[h][j + 4], w5 = s_w[h][j + 5], w6 = s_w[h][j + 6], w7 = s_w[h][j + 7];
        EDGE_FMA(p0, w0) EDGE_FMA(p1, w1) EDGE_FMA(p2, w2) EDGE_FMA(p3, w3)
        EDGE_FMA(p4, w4) EDGE_FMA(p5, w5) EDGE_FMA(p6, w6) EDGE_FMA(p7, w7)
    }
    for (; j + 4 <= cnt; j += 4) {
        unsigned int p0 = *(const unsigned int*)&hb[s_r[h][j    ] + c];
        unsigned int p1 = *(const unsigned int*)&hb[s_r[h][j + 1] + c];
        unsigned int p2 = *(const unsigned int*)&hb[s_r[h][j + 2] + c];
        unsigned int p3 = *(const unsigned int*)&hb[s_r[h][j + 3] + c];
        float w0 = s_w[h][j], w1 = s_w[h][j + 1], w2 = s_w[h][j + 2], w3 = s_w[h][j + 3];
        EDGE_FMA(p0, w0) EDGE_FMA(p1, w1) EDGE_FMA(p2, w2) EDGE_FMA(p3, w3)
    }
    for (; j < cnt; j++) {
        unsigned int p0 = *(const unsigned int*)&hb[s_r[h][j] + c];
        float w0 = s_w[h][j];
        EDGE_FMA(p0, w0)
    }

    float2 o;
    o.x = (a0 + bflo(hv) * dv) * dv + bv.x;
    o.y = (a1 + bfhi(hv) * dv) * dv + bv.y;
    *(float2*)&out[(size_t)i * DD + c] = o;
}

extern "C" void kernel_launch(void* const* d_in, const int* in_sizes, int n_in,
                              void* d_out, int out_size, void* d_ws, size_t ws_size,
                              hipStream_t stream) {
    const float* x  = (const float*)d_in[0];
    const int*   ei = (const int*)d_in[1];
    const float* ea = (const float*)d_in[2];
    const float* W  = (const float*)d_in[3];
    const float* b  = (const float*)d_in[4];
    float* out = (float*)d_out;

    char* ws = (char*)d_ws;
    unsigned short* hb   = (unsigned short*)ws;                 // 10,240,000 B
    unsigned short* xb   = (unsigned short*)(ws + 10240000);    // 10,240,000 B
    unsigned short* wtb  = (unsigned short*)(ws + 20480000);    // 524,288 B
    float* deg    = (float*)(ws + 21004288);                    // 40,960 B
    int*   cursor = (int*)  (ws + 21045248);                    // 40,960 B
    uint2* erw    = (uint2*)(ws + 21086208);                    // 10,240,000 B

    const int* row = ei;
    const int* col = ei + EE;

    hipMemsetAsync(deg, 0, 81920, stream);   // deg + cursor (contiguous)

    k_prep_xw<<<XB_BLOCKS + WT_BLOCKS, 256, 0, stream>>>(x, W, xb, wtb);

    k_gemm_edge<<<EDGE_BLOCKS + GM_BLOCKS, 256, 0, stream>>>(xb, wtb, hb, row, col, ea,
                                                             deg, cursor, erw);

    k_aggregate<<<NN * 2, 128, 0, stream>>>(cursor, erw, hb, deg, b, out);
}

// Round 5
// 128.483 us; speedup vs baseline: 1.0307x; 1.0273x over previous
//
#include <hip/hip_runtime.h>

#define NN 10000
#define EE 160000
#define DD 512
#define CAP 128   // bucket capacity; deg ~ Poisson(16), P(>=128) ~ 0 (writes clamped)

typedef float floatx4 __attribute__((ext_vector_type(4)));
typedef short short8 __attribute__((ext_vector_type(8)));

#define AS3(p) ((__attribute__((address_space(3))) void*)(p))
#define AS1(p) ((const __attribute__((address_space(1))) void*)(p))

static __device__ __forceinline__ unsigned short f2bf(float f) {
    unsigned int u = __float_as_uint(f);
    unsigned int r = (u + 0x7fffu + ((u >> 16) & 1u)) >> 16;
    return (unsigned short)r;
}
// HW packed convert: lo16 = bf16(a), hi16 = bf16(b). RNE, 1 instr (gfx950; no builtin).
static __device__ __forceinline__ unsigned int cvtpk(float a, float b) {
    unsigned int r;
    asm("v_cvt_pk_bf16_f32 %0, %1, %2" : "=v"(r) : "v"(a), "v"(b));
    return r;
}
static __device__ __forceinline__ float bflo(unsigned int u) {
    return __uint_as_float(u << 16);
}
static __device__ __forceinline__ float bfhi(unsigned int u) {
    return __uint_as_float(u & 0xffff0000u);
}

// ---------------- prep: x->bf16 | W->W^T bf16 (LDS-tiled) | zero deg/cursor ----------------

#define XB_BLOCKS 5000
#define WT_BLOCKS 256
#define ZERO_BLOCKS 20
#define EDGE_BLOCKS 625
#define GM_BLOCKS (157 * 4)   // 64-row tiles x 4 col-tiles of 128

__global__ __launch_bounds__(256) void k_prep_xw(const float* __restrict__ x,
                                                 const float* __restrict__ W,
                                                 unsigned short* __restrict__ xb,
                                                 unsigned short* __restrict__ wtb,
                                                 uint4* __restrict__ zbase) {
    const int b = blockIdx.x;
    const int tid = threadIdx.x;
    if (b < XB_BLOCKS) {
        int gid = b * 256 + tid;                     // float4 group of x
        float4 v = *(const float4*)&x[(size_t)gid * 4];
        *(uint2*)&xb[(size_t)gid * 4] = make_uint2(cvtpk(v.x, v.y), cvtpk(v.z, v.w));
    } else if (b < XB_BLOCKS + WT_BLOCKS) {
        __shared__ float T[32][33];
        int idx = b - XB_BLOCKS;
        int bi = idx & 15;        // k-tile
        int bj = idx >> 4;        // n-tile
        int r0 = tid >> 5;        // 0..7
        int cc = tid & 31;
        #pragma unroll
        for (int k = 0; k < 4; k++) {
            int r = r0 + k * 8;
            T[r][cc] = W[(size_t)(bi * 32 + r) * DD + bj * 32 + cc];
        }
        __syncthreads();
        #pragma unroll
        for (int k = 0; k < 4; k++) {
            int r = r0 + k * 8;
            wtb[(size_t)(bj * 32 + r) * DD + bi * 32 + cc] = f2bf(T[cc][r]);   // wtb[n][k]=W[k][n]
        }
    } else {
        // zero deg + cursor: 20 blocks x 256 thr x 16 B = 81920 B
        int idx = (b - XB_BLOCKS - WT_BLOCKS) * 256 + tid;
        zbase[idx] = make_uint4(0u, 0u, 0u, 0u);
    }
}

// ---------------- fused: edge bucket/deg build (625 blocks) + MFMA GEMM (628 blocks) ----------------
// R1-exact GEMM: single-buffer LDS, A from xb bf16 via async global_load_lds.
// GEMM has no dependency on deg -> latency-bound edge atomics overlap with MFMA blocks.

__global__ __launch_bounds__(256) void k_gemm_edge(const unsigned short* __restrict__ xb,
                                                   const unsigned short* __restrict__ wtb,
                                                   unsigned short* __restrict__ hb,
                                                   const int* __restrict__ row,
                                                   const int* __restrict__ col,
                                                   const float* __restrict__ ew,
                                                   float* __restrict__ deg,
                                                   int* __restrict__ cursor,
                                                   uint2* __restrict__ erw) {
    __shared__ unsigned short As[64 * 32];    // 4 KB
    __shared__ unsigned short Bs[128 * 32];   // 8 KB

    const int tid = threadIdx.x;

    if (blockIdx.x < EDGE_BLOCKS) {
        // -------- edge pass: deg accum + bucket build --------
        int e = blockIdx.x * 256 + tid;        // exactly covers EE
        int r = row[e];
        int t = col[e];
        float w = ew[e];
        atomicAdd(&deg[t], w);
        int p = atomicAdd(&cursor[t], 1);
        if (p < CAP) erw[t * CAP + p] = make_uint2((unsigned int)r, __float_as_uint(w));
        return;
    }

    // -------- GEMM: hb = bf16(xb @ wtb^T), 64x128 tile --------
    const int bid = blockIdx.x - EDGE_BLOCKS;
    const int wave = tid >> 6;
    const int lane = tid & 63;

    const int bm = (bid >> 2) * 64;
    const int bn = (bid & 3) * 128;

    const int wm = (wave >> 1) * 32;   // 0 / 32
    const int wn = (wave & 1) * 64;    // 0 / 64

    const int fm = lane & 15;
    const int kb = (lane >> 4) * 8;

    floatx4 acc[2][4];
    #pragma unroll
    for (int i = 0; i < 2; i++)
        #pragma unroll
        for (int j = 0; j < 4; j++)
            acc[i][j] = (floatx4){0.f, 0.f, 0.f, 0.f};

    const int srow = lane >> 2;          // 0..15 within a 16-row chunk
    const int scol = (lane & 3) * 8;     // 0,8,16,24

    for (int k0 = 0; k0 < DD; k0 += 32) {
        // A: 64 rows, one chunk per wave
        {
            int r = wave * 16 + srow;
            int gr = bm + r; if (gr > NN - 1) gr = NN - 1;   // clamp (stores guarded)
            __builtin_amdgcn_global_load_lds(AS1(xb + (size_t)gr * DD + k0 + scol),
                                             AS3(&As[wave * 512]), 16, 0, 0);
        }
        // B: 128 rows, two chunks per wave
        #pragma unroll
        for (int cc = 0; cc < 2; cc++) {
            int c = wave + cc * 4;
            int nr = bn + c * 16 + srow;
            __builtin_amdgcn_global_load_lds(AS1(wtb + (size_t)nr * DD + k0 + scol),
                                             AS3(&Bs[c * 512]), 16, 0, 0);
        }
        __syncthreads();

        short8 af[2], bfr[4];
        #pragma unroll
        for (int mi = 0; mi < 2; mi++)
            af[mi] = *(const short8*)&As[(wm + mi * 16 + fm) * 32 + kb];
        #pragma unroll
        for (int ni = 0; ni < 4; ni++)
            bfr[ni] = *(const short8*)&Bs[(wn + ni * 16 + fm) * 32 + kb];

        #pragma unroll
        for (int mi = 0; mi < 2; mi++)
            #pragma unroll
            for (int ni = 0; ni < 4; ni++)
                acc[mi][ni] = __builtin_amdgcn_mfma_f32_16x16x32_bf16(af[mi], bfr[ni], acc[mi][ni], 0, 0, 0);

        __syncthreads();
    }

    #pragma unroll
    for (int mi = 0; mi < 2; mi++) {
        #pragma unroll
        for (int ni = 0; ni < 4; ni++) {
            int colg = bn + wn + ni * 16 + (lane & 15);
            int rbase = bm + wm + mi * 16 + (lane >> 4) * 4;
            #pragma unroll
            for (int j = 0; j < 4; j++) {
                int rg = rbase + j;
                if (rg < NN) hb[(size_t)rg * DD + colg] = f2bf(acc[mi][ni][j]);
            }
        }
    }
}

// ---------------- aggregate: column-QUARTER split, XCD binding (R2-measured) ----------------
// Block bid (128 thr = 2 waves): quarter q = bid&3, wave h handles node (bid>>2)*2 + h,
// columns [q*128, q*128+128), 2 bf16 cols/lane. Round-robin block->XCD dispatch binds
// quarter q to XCDs {q, q+4} -> per-XCD hb working set 2.56 MB < 4 MB L2 -> gathers
// L2-resident instead of L3. dinv[row] folded at bucket-stage time; hb holds raw h.

#define EDGE_FMA(P, W) a0 += bflo(P) * W; a1 += bfhi(P) * W;

__global__ __launch_bounds__(128, 8) void k_aggregate(const int* __restrict__ cursor,
                                                      const uint2* __restrict__ erw,
                                                      const unsigned short* __restrict__ hb,
                                                      const float* __restrict__ deg,
                                                      const float* __restrict__ bias,
                                                      float* __restrict__ out) {
    const int h = threadIdx.x >> 6;
    const int t = threadIdx.x & 63;
    const int bid = blockIdx.x;                // 0..19999
    const int q = bid & 3;
    const int i = (bid >> 2) * 2 + h;          // node
    const int c = q * 128 + t * 2;             // bf16 col index, 2 cols/lane

    __shared__ int   s_r[2][CAP];              // precomputed row*DD element base
    __shared__ float s_w[2][CAP];

    int cnt = cursor[i];
    if (cnt > CAP) cnt = CAP;
    const uint2* bkt = erw + (size_t)i * CAP;
    if (t < cnt) {
        uint2 p = bkt[t];
        int r = (int)p.x;
        s_r[h][t] = r << 9;                    // r * DD
        s_w[h][t] = __uint_as_float(p.y) * rsqrtf(deg[r] + 1.0f);
    }
    if (t + 64 < cnt) {
        uint2 p = bkt[t + 64];
        int r = (int)p.x;
        s_r[h][t + 64] = r << 9;
        s_w[h][t + 64] = __uint_as_float(p.y) * rsqrtf(deg[r] + 1.0f);
    }

    // hoist self-row + bias
    float dv = rsqrtf(deg[i] + 1.0f);
    unsigned int hv = *(const unsigned int*)&hb[(size_t)i * DD + c];
    float2 bv = *(const float2*)&bias[c];

    __syncthreads();

    float a0 = 0.f, a1 = 0.f;

    int j = 0;
    for (; j + 8 <= cnt; j += 8) {
        unsigned int p0 = *(const unsigned int*)&hb[s_r[h][j    ] + c];
        unsigned int p1 = *(const unsigned int*)&hb[s_r[h][j + 1] + c];
        unsigned int p2 = *(const unsigned int*)&hb[s_r[h][j + 2] + c];
        unsigned int p3 = *(const unsigned int*)&hb[s_r[h][j + 3] + c];
        unsigned int p4 = *(const unsigned int*)&hb[s_r[h][j + 4] + c];
        unsigned int p5 = *(const unsigned int*)&hb[s_r[h][j + 5] + c];
        unsigned int p6 = *(const unsigned int*)&hb[s_r[h][j + 6] + c];
        unsigned int p7 = *(const unsigned int*)&hb[s_r[h][j + 7] + c];
        float w0 = s_w[h][j],     w1 = s_w[h][j + 1], w2 = s_w[h][j + 2], w3 = s_w[h][j + 3];
        float w4 = s_w[h][j + 4], w5 = s_w[h][j + 5], w6 = s_w[h][j + 6], w7 = s_w[h][j + 7];
        EDGE_FMA(p0, w0) EDGE_FMA(p1, w1) EDGE_FMA(p2, w2) EDGE_FMA(p3, w3)
        EDGE_FMA(p4, w4) EDGE_FMA(p5, w5) EDGE_FMA(p6, w6) EDGE_FMA(p7, w7)
    }
    for (; j + 4 <= cnt; j += 4) {
        unsigned int p0 = *(const unsigned int*)&hb[s_r[h][j    ] + c];
        unsigned int p1 = *(const unsigned int*)&hb[s_r[h][j + 1] + c];
        unsigned int p2 = *(const unsigned int*)&hb[s_r[h][j + 2] + c];
        unsigned int p3 = *(const unsigned int*)&hb[s_r[h][j + 3] + c];
        float w0 = s_w[h][j], w1 = s_w[h][j + 1], w2 = s_w[h][j + 2], w3 = s_w[h][j + 3];
        EDGE_FMA(p0, w0) EDGE_FMA(p1, w1) EDGE_FMA(p2, w2) EDGE_FMA(p3, w3)
    }
    for (; j < cnt; j++) {
        unsigned int p0 = *(const unsigned int*)&hb[s_r[h][j] + c];
        float w0 = s_w[h][j];
        EDGE_FMA(p0, w0)
    }

    float2 o;
    o.x = (a0 + bflo(hv) * dv) * dv + bv.x;
    o.y = (a1 + bfhi(hv) * dv) * dv + bv.y;
    *(float2*)&out[(size_t)i * DD + c] = o;
}

extern "C" void kernel_launch(void* const* d_in, const int* in_sizes, int n_in,
                              void* d_out, int out_size, void* d_ws, size_t ws_size,
                              hipStream_t stream) {
    const float* x  = (const float*)d_in[0];
    const int*   ei = (const int*)d_in[1];
    const float* ea = (const float*)d_in[2];
    const float* W  = (const float*)d_in[3];
    const float* b  = (const float*)d_in[4];
    float* out = (float*)d_out;

    char* ws = (char*)d_ws;
    unsigned short* hb   = (unsigned short*)ws;                 // 10,240,000 B
    unsigned short* xb   = (unsigned short*)(ws + 10240000);    // 10,240,000 B
    unsigned short* wtb  = (unsigned short*)(ws + 20480000);    // 524,288 B
    float* deg    = (float*)(ws + 21004288);                    // 40,960 B
    int*   cursor = (int*)  (ws + 21045248);                    // 40,960 B
    uint2* erw    = (uint2*)(ws + 21086208);                    // 10,240,000 B

    const int* row = ei;
    const int* col = ei + EE;

    k_prep_xw<<<XB_BLOCKS + WT_BLOCKS + ZERO_BLOCKS, 256, 0, stream>>>(x, W, xb, wtb, (uint4*)deg);

    k_gemm_edge<<<EDGE_BLOCKS + GM_BLOCKS, 256, 0, stream>>>(xb, wtb, hb, row, col, ea,
                                                             deg, cursor, erw);

    k_aggregate<<<NN * 2, 128, 0, stream>>>(cursor, erw, hb, deg, b, out);
}